// Round 6
// baseline (345.365 us; speedup 1.0000x reference)
//
#include <hip/hip_runtime.h>
#include <cstdint>

// Problem constants (from the reference)
#define LL    200
#define QQ    21
#define MM    1024
#define START 133        // 2*L//3
#define NS    67         // L - START
#define RGH   0.01f
#define RGJ   0.01f

// ws layout:
//   [0, 1024)              : accumulator slots (3 x 64 fp32)
//   [1024, +TOKP)          : tokP packed tokens, 4 j per dword, [jq][n]
//   [TOKP end, +SLAB)      : logit slab [iI][a][n], atomic-accumulated
#define SLOT_J2  0
#define SLOT_E   64
#define SLOT_LZ  128
#define TOKP_W   52
#define TOKP_OFF 1024
#define TOKP_BYTES ((size_t)TOKP_W * MM * 4)
#define SLAB_OFF (TOKP_OFF + TOKP_BYTES)
#define SLAB_FLOATS ((size_t)NS * QQ * MM)
#define SLAB_BYTES (SLAB_FLOATS * 4)
#define WS_FULL (SLAB_OFF + SLAB_BYTES)
#define WS_TOK  SLAB_OFF

// R1-R5 invariant: ~1300 cyc per j per CU across ALL structures => CU LDS
// pipe is data-path bound at dword width (~44 B/cyc; read2 = 2 addresses =
// same rate, which is why R5 was null). Fix: TRANSPOSED tile [c=j*21+b][a]
// (a-stride 1) so one (n,j) gather = 10 ds_read_b64 + 1 ds_read_b32 from ONE
// base reg + imm offsets (<=80B) -> ~85 B/cyc, ~2x per dword.
//  - read banks: c-stride 21 dwords, gcd(21,32)=1 -> 21 distinct bases,
//    b64 spans 2 -> ~1.3-way ~= free (2-way is free, m136)
//  - staging: global_load_lds can't transpose -> reg-staged: 11 uniform
//    coalesced dword loads/thread (lanes span c -> 256B bursts, L2-hot for
//    the z-pair), per-thread CONTIGUOUS a-run writes (compiler merges to
//    b128/b64; lane-stride 21 -> conflict-free)
#define TJ 12
#define CPT (TJ * QQ)                  // 252 real columns
#define DUMP_DW 5292                   // dump row for fake writes
#define TILE_DW 5312                   // 5292 + 11 dump + pad (21248 B)
#define NBUF 2
#define BT 512
#define NWAVE 8

// Balanced p1 schedule: flatten (site, j-quad) -> [0, Tz) cut into NB_R
// equal ranges (~11 quads); block bx = (range bx&255, z-half bx>>8).
// z-pair blocks co-reside per CU and load identical J tiles (L2-hot).
#define NB_R  256
#define NB_P1 (2 * NB_R)               // 512
#define NB_JS 512
#define NB_TOKP 512

typedef float __attribute__((address_space(3)))* lf3_t;
typedef float __attribute__((ext_vector_type(2))) f32x2;

template <int NW>
__device__ __forceinline__ float block_reduce_sum(float v) {
  __shared__ float sm[NW];
  #pragma unroll
  for (int off = 32; off > 0; off >>= 1) v += __shfl_down(v, off, 64);
  const int lane = threadIdx.x & 63;
  const int wv   = threadIdx.x >> 6;
  __syncthreads();
  if (lane == 0) sm[wv] = v;
  __syncthreads();
  float r = 0.0f;
  if (threadIdx.x == 0) {
    #pragma unroll
    for (int k = 0; k < NW; ++k) r += sm[k];
  }
  return r;  // valid in thread 0 only
}

// ---------------------------------------------------------------------------
// Stage loads: jr[r] = J[i, 11*hi + r, j0*21 + tl]; lanes span tl ->
// 256 B coalesced per r. Invalid (tl>=252 | gc>=4200 | a==21) -> safe Ji[0].
// Full 252-column tile staged even for partial j-ranges (rows j>=jend are
// garbage but never gathered).
// ---------------------------------------------------------------------------
__device__ __forceinline__ void stage_load(
    const float* __restrict__ Ji, int j0, int tl, int hi, float (&jr)[11]) {
  const int gc = j0 * QQ + tl;
  const bool okc = (tl < CPT) && (gc < LL * QQ);
  const float* g0 = Ji + (size_t)(11 * hi) * (LL * QQ) + gc;
  #pragma unroll
  for (int r = 0; r < 11; ++r) {
    const bool ok = okc && (hi == 0 || r < 10);   // hi wave-uniform
    const float* ga = ok ? (g0 + r * (LL * QQ)) : Ji;
    jr[r] = *ga;
  }
}

// Writes: per-thread contiguous run tile[tl*21 + 11*hi + r], r=0..10(hi=0)
// or 0..9(hi=1) -> compiler merges into b128/b64/b32. Lane-stride 21 dwords
// -> all banks distinct -> conflict-free. Invalid threads -> dump row.
__device__ __forceinline__ void stage_write(
    float* __restrict__ wp, int hi, const float (&jr)[11]) {
  #pragma unroll
  for (int r = 0; r < 10; ++r) wp[r] = jr[r];
  if (hi == 0) wp[10] = jr[10];        // wave-uniform branch
}

// ---------------------------------------------------------------------------
// Load the 3 packed token words covering tile at j0 (12 j's, j0 % 4 == 0).
// Fully-fake tiles (j0 >= jend) reload tile-0's words (never consumed).
// ---------------------------------------------------------------------------
template <int USET>
__device__ __forceinline__ void tok_words(
    const uint32_t* __restrict__ tokP, const int* __restrict__ Xtok,
    int j0, int jbeg, int jend, int n, uint32_t (&tw)[3]) {
  const int wbase = ((j0 < jend) ? j0 : jbeg) >> 2;
  #pragma unroll
  for (int wi = 0; wi < 3; ++wi) {
    int wq = wbase + wi;
    if constexpr (USET) {
      tw[wi] = tokP[wq * MM + n];        // words 50/51 = pad, never consumed
    } else {
      if (wq >= LL / 4) wq -= (LL / 4 - 1);   // keep in-bounds, distinct
      const int4 x = *reinterpret_cast<const int4*>(Xtok + n * LL + 4 * wq);
      tw[wi] = (uint32_t)x.x | ((uint32_t)x.y << 8)
             | ((uint32_t)x.z << 16) | ((uint32_t)x.w << 24);
    }
  }
}

// ---------------------------------------------------------------------------
// Gather one j: 21 consecutive dwords at tile[(jl*21+b)*21] via 10 b64 + 1
// b32, single base reg + imm offsets. Rule #18: consume only after in-asm
// lgkmcnt(0) + sched_barrier(0).
// ---------------------------------------------------------------------------
#define RD64(dst, p, OFS) \
  asm volatile("ds_read_b64 %0, %1 offset:" #OFS \
               : "=v"(dst) : "v"((lf3_t)(p)))

__device__ __forceinline__ void gather_j(
    const float* __restrict__ tile, int cdw, float (&lg)[QQ]) {
  const float* p = tile + cdw;
  f32x2 g0, g1, g2, g3, g4, g5, g6, g7, g8, g9;
  float g20;
  RD64(g0, p, 0);  RD64(g1, p, 8);  RD64(g2, p, 16); RD64(g3, p, 24);
  RD64(g4, p, 32); RD64(g5, p, 40); RD64(g6, p, 48); RD64(g7, p, 56);
  RD64(g8, p, 64); RD64(g9, p, 72);
  asm volatile("ds_read_b32 %0, %1 offset:80" : "=v"(g20) : "v"((lf3_t)p));
  asm volatile("s_waitcnt lgkmcnt(0)" ::: "memory");
  __builtin_amdgcn_sched_barrier(0);
  lg[0]  += g0.x; lg[1]  += g0.y; lg[2]  += g1.x; lg[3]  += g1.y;
  lg[4]  += g2.x; lg[5]  += g2.y; lg[6]  += g3.x; lg[7]  += g3.y;
  lg[8]  += g4.x; lg[9]  += g4.y; lg[10] += g5.x; lg[11] += g5.y;
  lg[12] += g6.x; lg[13] += g6.y; lg[14] += g7.x; lg[15] += g7.y;
  lg[16] += g8.x; lg[17] += g8.y; lg[18] += g9.x; lg[19] += g9.y;
  lg[20] += g20;
}

// ---------------------------------------------------------------------------
// One segment: lg[a] += J[i,a,j,b(n,j)] over j in [jbeg, jend), jbeg%4==0.
// NBUF=2, one barrier/tile. Per iter: issue reg-stage loads (s+1) + token
// prefetch (s+2) BEFORE the gather (sched_barrier-pinned); write after the
// gather (compiler inserts the vmcnt wait at first jr use — covered by the
// ~1k-cyc gather). Early stores into buf[cur^1] are safe: its readers
// drained at the previous barrier.
// ---------------------------------------------------------------------------
template <int USET>
__device__ __forceinline__ void logz_seg(
    const float* __restrict__ Ji, const uint32_t* __restrict__ tokP,
    const int* __restrict__ Xtok, int jbeg, int jend, int n,
    float (*lds)[TILE_DW], float (&lg)[QQ], int t) {
  const int ntiles = (jend - jbeg + TJ - 1) / TJ;   // >= 1
  const int tl = t & 255, hi = t >> 8;              // hi wave-uniform
  const int wdw = (tl < CPT) ? (tl * QQ + 11 * hi) : DUMP_DW;
  float* const wpA = &lds[0][wdw];
  float* const wpB = &lds[1][wdw];

  uint32_t cw[3], nx[3], nn[3];
  float jr[11];

  // Prologue: stage tile 0 into buf0; tokens for tiles 0,1.
  stage_load(Ji, jbeg, tl, hi, jr);
  tok_words<USET>(tokP, Xtok, jbeg, jbeg, jend, n, cw);
  tok_words<USET>(tokP, Xtok, jbeg + TJ, jbeg, jend, n, nx);
  stage_write(wpA, hi, jr);
  asm volatile("s_waitcnt lgkmcnt(0)" ::: "memory");
  __builtin_amdgcn_s_barrier();
  __builtin_amdgcn_sched_barrier(0);

  int cur = 0;
  for (int s = 0; s < ntiles; ++s) {
    const int rem  = min(TJ, jend - (jbeg + s * TJ));
    const bool more = (s + 1 < ntiles);             // block-uniform
    if (more) stage_load(Ji, jbeg + (s + 1) * TJ, tl, hi, jr);
    tok_words<USET>(tokP, Xtok, jbeg + (s + 2) * TJ, jbeg, jend, n, nn);
    __builtin_amdgcn_sched_barrier(0);              // pin loads above gather
    const float* tb = cur ? lds[1] : lds[0];
    #pragma unroll
    for (int jl = 0; jl < TJ; ++jl) {
      if (jl >= rem) break;                         // block-uniform
      const int b = (int)((cw[jl >> 2] >> ((jl & 3) * 8)) & 0xFF);
      gather_j(tb, (jl * QQ + b) * QQ, lg);
    }
    if (more) stage_write(cur ? wpA : wpB, hi, jr); // into buf[cur^1]
    #pragma unroll
    for (int wi = 0; wi < 3; ++wi) { cw[wi] = nx[wi]; nx[wi] = nn[wi]; }
    asm volatile("s_waitcnt lgkmcnt(0)" ::: "memory");
    __builtin_amdgcn_s_barrier();
    __builtin_amdgcn_sched_barrier(0);
    cur ^= 1;
  }
}

// ---------------------------------------------------------------------------
// p1 block: balanced quad-schedule per z-half. Range r owns quads
// [r*Tz/NB_R, (r+1)*Tz/NB_R); spans <=2 sites; atomic-flush into slab.
// ---------------------------------------------------------------------------
__device__ __forceinline__ void p1_block(
    const float* __restrict__ J, const uint32_t* __restrict__ tokP,
    float* __restrict__ slab, int bx, float (*lds)[TILE_DW]) {
  const int t = threadIdx.x;
  const int r = bx & (NB_R - 1);
  const int z = bx >> 8;

  int Tz = 0;                          // constant-folds
  #pragma unroll
  for (int s2 = 0; s2 < NS; ++s2) Tz += (START + s2 + 3) >> 2;

  int g  = (r * Tz) / NB_R;
  const int g1 = ((r + 1) * Tz) / NB_R;
  int iI = 0, pref = 0;
  while (pref + ((START + iI + 3) >> 2) <= g) {
    pref += (START + iI + 3) >> 2;
    ++iI;
  }
  int qlo = g - pref;

  float lg[QQ];
  #pragma unroll
  for (int a = 0; a < QQ; ++a) lg[a] = 0.0f;

  while (g < g1) {
    const int i    = START + iI;
    const int qcap = (i + 3) >> 2;
    int qhi = qlo + (g1 - g);
    if (qhi > qcap) qhi = qcap;
    const int jbeg = qlo * 4;
    int jend = qhi * 4; if (jend > i) jend = i;
    const int n = z * BT + t;
    const float* Ji = J + (size_t)i * (QQ * LL * QQ);

    logz_seg<1>(Ji, tokP, nullptr, jbeg, jend, n, lds, lg, t);

    float* dst = slab + ((size_t)iI * QQ) * MM + n;
    #pragma unroll
    for (int a = 0; a < QQ; ++a) { atomicAdd(dst + a * MM, lg[a]); lg[a] = 0.0f; }

    g += qhi - qlo;
    qlo = 0; ++iI;
  }
}

// ---------------------------------------------------------------------------
// jsum body: sum(J^2) stream + sum(J*fij) prefix rows, grid-strided by jb.
// ---------------------------------------------------------------------------
__device__ __forceinline__ void jsum_body(
    const float* __restrict__ J, const float* __restrict__ fij,
    float* __restrict__ acc, int jb) {
  const int t = threadIdx.x;
  const float4* __restrict__ J4 = (const float4*)J;
  float j2 = 0.0f;
  for (int f = jb * BT + t; f < (LL * QQ * LL * QQ / 4); f += NB_JS * BT) {
    const float4 v = J4[f];
    j2 += v.x * v.x + v.y * v.y + v.z * v.z + v.w * v.w;
  }
  float e = 0.0f;
  for (int r = jb; r < NS * QQ; r += NB_JS) {
    const int iI = r / QQ;
    const int a  = r - iI * QQ;
    const int i  = START + iI;
    const size_t base = (size_t)i * (QQ * LL * QQ) + (size_t)a * (LL * QQ);
    const float4* __restrict__ Jb = (const float4*)(J + base);
    const float4* __restrict__ Fb = (const float4*)(fij + base);
    const int lim  = i * QQ;
    const int lim4 = lim >> 2;
    for (int f = t; f < lim4; f += BT) {
      const float4 v = Jb[f], u = Fb[f];
      e += v.x * u.x + v.y * u.y + v.z * u.z + v.w * u.w;
    }
    const int rem = lim & 3;
    if (t < rem) {
      const int p = lim4 * 4 + t;
      e += (J + base)[p] * (fij + base)[p];
    }
  }
  const float tj2 = block_reduce_sum<NWAVE>(j2);
  const float te  = block_reduce_sum<NWAVE>(e);
  if (t == 0) {
    atomicAdd(acc + SLOT_J2 + (jb & 63), tj2);
    atomicAdd(acc + SLOT_E  + (jb & 63), te);
  }
}

// ---------------------------------------------------------------------------
// Fused kernel: blocks [0, NB_P1) = p1 (2 z-paired per CU), then jsum
// fillers (HBM-bound) on the 3rd block slot + makespan tail.
// ---------------------------------------------------------------------------
__global__ __launch_bounds__(BT, 6) void kern_mega(
    const float* __restrict__ J, const float* __restrict__ fij,
    const uint32_t* __restrict__ tokP, float* __restrict__ slab,
    float* __restrict__ acc) {
  __shared__ float lds[NBUF][TILE_DW];
  const int bx = blockIdx.x;
  if (bx < NB_P1) p1_block(J, tokP, slab, bx, lds);
  else            jsum_body(J, fij, acc, bx - NB_P1);
}

// ---------------------------------------------------------------------------
// Fallback (ws too small for slab): full-range mono blocks with in-kernel
// logsumexp. Grid (NS, 1, 2), z = blockIdx.z.
// ---------------------------------------------------------------------------
template <int USET>
__device__ __forceinline__ void mono_body(
    const float* __restrict__ J, const uint32_t* __restrict__ tokP,
    const int* __restrict__ Xtok, const float* __restrict__ h,
    const float* __restrict__ w, float* __restrict__ acc,
    float (*lds)[TILE_DW]) {
  const int iI = blockIdx.x;
  const int i  = START + iI;
  const int t  = threadIdx.x;
  const int n  = blockIdx.z * BT + t;
  float lg[QQ];
  #pragma unroll
  for (int a = 0; a < QQ; ++a) lg[a] = 0.0f;
  logz_seg<USET>(J + (size_t)i * (QQ * LL * QQ), tokP, Xtok, 0, i, n,
                 lds, lg, t);
  const float* hi = h + i * QQ;
  float mx = -3.0e38f;
  #pragma unroll
  for (int a = 0; a < QQ; ++a) { lg[a] += hi[a]; mx = fmaxf(mx, lg[a]); }
  float sme = 0.0f;
  #pragma unroll
  for (int a = 0; a < QQ; ++a) sme += expf(lg[a] - mx);
  const float contrib = w[n] * (mx + logf(sme));
  const float tot = block_reduce_sum<NWAVE>(contrib);
  if (t == 0) atomicAdd(acc + SLOT_LZ + (iI & 63), tot);
}

__global__ __launch_bounds__(BT) void kern_logz_mono_t(
    const float* __restrict__ J, const uint32_t* __restrict__ tokP,
    const float* __restrict__ h, const float* __restrict__ w,
    float* __restrict__ acc) {
  __shared__ float lds[NBUF][TILE_DW];
  mono_body<1>(J, tokP, nullptr, h, w, acc, lds);
}

__global__ __launch_bounds__(BT) void kern_logz_mono_x(
    const float* __restrict__ J, const int* __restrict__ Xtok,
    const float* __restrict__ h, const float* __restrict__ w,
    float* __restrict__ acc) {
  __shared__ float lds[NBUF][TILE_DW];
  mono_body<0>(J, nullptr, Xtok, h, w, acc, lds);
}

__global__ __launch_bounds__(BT) void kern_jsum(
    const float* __restrict__ J, const float* __restrict__ fij,
    float* __restrict__ acc) {
  jsum_body(J, fij, acc, blockIdx.x);
}

// ---------------------------------------------------------------------------
// Phase 2: slab + h -> logsumexp -> weighted sum (fence-free).
// ---------------------------------------------------------------------------
__global__ __launch_bounds__(128) void kern_logz_p2(
    const float* __restrict__ slab, const float* __restrict__ h,
    const float* __restrict__ w, float* __restrict__ acc) {
  const int iI = blockIdx.x;
  const int n  = blockIdx.y * 128 + threadIdx.x;
  const float* s0 = slab + ((size_t)iI * QQ) * MM + n;
  const float* hi = h + (START + iI) * QQ;
  float lg[QQ];
  float mx = -3.0e38f;
  #pragma unroll
  for (int a = 0; a < QQ; ++a) {
    lg[a] = s0[a * MM] + hi[a];
    mx = fmaxf(mx, lg[a]);
  }
  float sme = 0.0f;
  #pragma unroll
  for (int a = 0; a < QQ; ++a) sme += expf(lg[a] - mx);
  float v = w[n] * (mx + logf(sme));
  #pragma unroll
  for (int off = 32; off > 0; off >>= 1) v += __shfl_down(v, off, 64);
  __shared__ float sm[2];
  if ((threadIdx.x & 63) == 0) sm[threadIdx.x >> 6] = v;
  __syncthreads();
  if (threadIdx.x == 0)
    atomicAdd(acc + SLOT_LZ + ((iI * 8 + blockIdx.y) & 63), sm[0] + sm[1]);
}

// ---------------------------------------------------------------------------
// Token packing + accumulator/slab zeroing.
// ---------------------------------------------------------------------------
__global__ __launch_bounds__(256) void kern_tokP(
    const int* __restrict__ X, uint32_t* __restrict__ tokP,
    float* __restrict__ slab, float* __restrict__ acc, int zslab) {
  const int idx = blockIdx.x * 256 + threadIdx.x;
  if (blockIdx.x == 0) acc[threadIdx.x] = 0.0f;
  if (idx < (LL / 4) * MM) {
    const int jq = idx / MM;
    const int n  = idx - jq * MM;
    const int4 x = *reinterpret_cast<const int4*>(X + n * LL + 4 * jq);
    tokP[idx] = (uint32_t)x.x | ((uint32_t)x.y << 8)
              | ((uint32_t)x.z << 16) | ((uint32_t)x.w << 24);
  }
  if (zslab) {
    float4* s4 = (float4*)slab;
    const int nf4 = (int)(SLAB_FLOATS / 4);
    for (int q = idx; q < nf4; q += NB_TOKP * 256)
      s4[q] = make_float4(0.f, 0.f, 0.f, 0.f);
  }
}

// ---------------------------------------------------------------------------
// Final combine: slot sums + h-side terms + weight normalization.
// ---------------------------------------------------------------------------
__global__ __launch_bounds__(256) void kern_final(
    const float* __restrict__ h, const float* __restrict__ fi,
    const float* __restrict__ w, const float* __restrict__ acc,
    float* __restrict__ out) {
  const int t = threadIdx.x;
  const float sj2 = block_reduce_sum<4>(t < 64 ? acc[SLOT_J2 + t] : 0.0f);
  const float se  = block_reduce_sum<4>(t < 64 ? acc[SLOT_E + t] : 0.0f);
  const float slz = block_reduce_sum<4>(t < 64 ? acc[SLOT_LZ + t] : 0.0f);
  float hs = 0.0f, eh = 0.0f, ws = 0.0f;
  for (int idx = t; idx < LL * QQ; idx += 256) {
    const float hv = h[idx];
    hs += hv * hv;
    if (idx >= START * QQ) eh += fi[idx] * hv;
  }
  for (int idx = t; idx < MM; idx += 256) ws += w[idx];
  const float ths = block_reduce_sum<4>(hs);
  const float teh = block_reduce_sum<4>(eh);
  const float tws = block_reduce_sum<4>(ws);
  if (t == 0) {
    const float energy = teh + se;
    const float nll = slz / tws - energy;
    out[0] = nll + RGH * ths + RGJ * sj2;
    out[1] = nll;
  }
}

extern "C" void kernel_launch(void* const* d_in, const int* in_sizes, int n_in,
                              void* d_out, int out_size, void* d_ws, size_t ws_size,
                              hipStream_t stream) {
  const int*   Xtok = (const int*)  d_in[0];
  const float* wts  = (const float*)d_in[1];
  const float* fi   = (const float*)d_in[2];
  const float* fij  = (const float*)d_in[3];
  const float* h    = (const float*)d_in[4];
  const float* J    = (const float*)d_in[5];
  float* out  = (float*)d_out;
  float* acc  = (float*)d_ws;
  uint32_t* tokP = (uint32_t*)((char*)d_ws + TOKP_OFF);
  float* slab = (float*)((char*)d_ws + SLAB_OFF);

  if (ws_size >= WS_FULL) {
    kern_tokP<<<NB_TOKP, 256, 0, stream>>>(Xtok, tokP, slab, acc, 1);
    kern_mega<<<NB_P1 + NB_JS, BT, 0, stream>>>(J, fij, tokP, slab, acc);
    kern_logz_p2<<<dim3(NS, 8), 128, 0, stream>>>(slab, h, wts, acc);
    kern_final<<<1, 256, 0, stream>>>(h, fi, wts, acc, out);
  } else if (ws_size >= WS_TOK) {
    kern_tokP<<<NB_TOKP, 256, 0, stream>>>(Xtok, tokP, nullptr, acc, 0);
    kern_jsum<<<NB_JS, BT, 0, stream>>>(J, fij, acc);
    kern_logz_mono_t<<<dim3(NS, 1, 2), BT, 0, stream>>>(J, tokP, h, wts, acc);
    kern_final<<<1, 256, 0, stream>>>(h, fi, wts, acc, out);
  } else {
    hipMemsetAsync(d_ws, 0, 1024, stream);
    kern_jsum<<<NB_JS, BT, 0, stream>>>(J, fij, acc);
    kern_logz_mono_x<<<dim3(NS, 1, 2), BT, 0, stream>>>(J, Xtok, h, wts, acc);
    kern_final<<<1, 256, 0, stream>>>(h, fi, wts, acc, out);
  }
}

// Round 7
// 189.768 us; speedup vs baseline: 1.8199x; 1.8199x over previous
//
#include <hip/hip_runtime.h>
#include <cstdint>

// Problem constants (from the reference)
#define LL    200
#define QQ    21
#define MM    1024
#define START 133        // 2*L//3
#define NS    67         // L - START
#define RGH   0.01f
#define RGJ   0.01f

// ws layout:
//   [0, 1024)              : accumulator slots (3 x 64 fp32)
//   [1024, +TOKP)          : tokP packed tokens, 4 j per dword, [jq][n]
//   [TOKP end, +SLAB)      : logit slab [iI][a][n], atomic-accumulated
#define SLOT_J2  0
#define SLOT_E   64
#define SLOT_LZ  128
#define TOKP_W   52
#define TOKP_OFF 1024
#define TOKP_BYTES ((size_t)TOKP_W * MM * 4)
#define SLAB_OFF (TOKP_OFF + TOKP_BYTES)
#define SLAB_FLOATS ((size_t)NS * QQ * MM)
#define SLAB_BYTES (SLAB_FLOATS * 4)
#define WS_FULL (SLAB_OFF + SLAB_BYTES)
#define WS_TOK  SLAB_OFF

// R6 post-mortem: transposed tile with row stride 21 dw (84 B) made half the
// ds_read_b64 addresses 4B-aligned -> gfx950 unaligned-DS slow path -> 4x
// collapse (VALUBusy 4.5%, conflicts 0, correct data). Fix: ROW STRIDE 22
// dwords (88 B == 0 mod 8) -> every b64 base and +8k offset naturally
// aligned. Banks: gcd(22,32)=2 -> 21 consecutive c-rows spread 16 banks,
// worst 2-way (free, m136).
// Tile [c = j*21+b][a], a-stride 1: gather per (n,j) = 10 ds_read_b64 +
// 1 ds_read_b32 off one base (offsets 0..80 B) -> 512 B/instr on the
// 128 B/cyc LDS data path (~2x the dword-grain rate that capped R1-R5 at
// ~1300 cyc/j/CU).
// Staging (global_load_lds can't transpose): reg-staged; hi half-block
// splits a-rows 12/9 so both write runs are 8B-aligned (offsets +0 / +48 B);
// lane stride 22 dw -> write conflict-free.
#define TJ 12
#define CPT (TJ * QQ)                  // 252 real columns
#define ROWDW 22                       // row stride (dwords), 88 B: 8B-aligned
#define DUMP_DW (CPT * ROWDW)          // dump row for invalid-thread writes
#define TILE_DW (DUMP_DW + ROWDW + 2)  // 5566 -> use 5568 (pad)
#define NBUF 2
#define BT 512
#define NWAVE 8

// Balanced p1 schedule: flatten (site, j-quad) -> [0, Tz) cut into NB_R
// equal ranges (~11 quads); block bx = (range bx&255, z-half bx>>8).
// z-pair blocks co-reside per CU and load identical J tiles (L2-hot).
#define NB_R  256
#define NB_P1 (2 * NB_R)               // 512
#define NB_JS 512
#define NB_TOKP 512

typedef float __attribute__((address_space(3)))* lf3_t;
typedef float __attribute__((ext_vector_type(2))) f32x2;

template <int NW>
__device__ __forceinline__ float block_reduce_sum(float v) {
  __shared__ float sm[NW];
  #pragma unroll
  for (int off = 32; off > 0; off >>= 1) v += __shfl_down(v, off, 64);
  const int lane = threadIdx.x & 63;
  const int wv   = threadIdx.x >> 6;
  __syncthreads();
  if (lane == 0) sm[wv] = v;
  __syncthreads();
  float r = 0.0f;
  if (threadIdx.x == 0) {
    #pragma unroll
    for (int k = 0; k < NW; ++k) r += sm[k];
  }
  return r;  // valid in thread 0 only
}

// ---------------------------------------------------------------------------
// Stage loads: thread tl covers global column gc = j0*21 + tl of plane
// [a][LL*QQ]; hi=0 waves load a=0..11 (12 rows), hi=1 waves a=12..20 (9).
// Lanes span gc -> 256 B coalesced per row. Invalid (tl>=252 | gc>=4200)
// -> safe Ji[0] (written to dump row, never gathered).
// ---------------------------------------------------------------------------
__device__ __forceinline__ void stage_load(
    const float* __restrict__ Ji, int j0, int tl, int hi, float (&jr)[12]) {
  const int gc = j0 * QQ + tl;
  const bool okc = (tl < CPT) && (gc < LL * QQ);
  const int a0 = hi ? 12 : 0;
  const int nr = hi ? 9 : 12;          // hi wave-uniform
  const float* g0 = Ji + (size_t)a0 * (LL * QQ) + gc;
  #pragma unroll
  for (int r = 0; r < 12; ++r) {
    if (r < nr) {
      const float* ga = okc ? (g0 + r * (LL * QQ)) : Ji;
      jr[r] = *ga;
    }
  }
}

// Writes: per-thread contiguous run at tile[tl*22 + (hi?12:0)]; both runs
// 8B-aligned (88*tl, +48 B) -> compiler merges to b64s; lane stride 22 dw
// -> conflict-free. Invalid threads -> dump row.
__device__ __forceinline__ void stage_write(
    float* __restrict__ wp, int hi, const float (&jr)[12]) {
  if (hi == 0) {
    #pragma unroll
    for (int r = 0; r < 12; ++r) wp[r] = jr[r];
  } else {
    #pragma unroll
    for (int r = 0; r < 9; ++r) wp[r] = jr[r];
  }
}

// ---------------------------------------------------------------------------
// Load the 3 packed token words covering tile at j0 (12 j's, j0 % 4 == 0).
// Fully-fake tiles (j0 >= jend) reload tile-0's words (never consumed).
// ---------------------------------------------------------------------------
template <int USET>
__device__ __forceinline__ void tok_words(
    const uint32_t* __restrict__ tokP, const int* __restrict__ Xtok,
    int j0, int jbeg, int jend, int n, uint32_t (&tw)[3]) {
  const int wbase = ((j0 < jend) ? j0 : jbeg) >> 2;
  #pragma unroll
  for (int wi = 0; wi < 3; ++wi) {
    int wq = wbase + wi;
    if constexpr (USET) {
      tw[wi] = tokP[wq * MM + n];        // words 50/51 = pad, never consumed
    } else {
      if (wq >= LL / 4) wq -= (LL / 4 - 1);   // keep in-bounds, distinct
      const int4 x = *reinterpret_cast<const int4*>(Xtok + n * LL + 4 * wq);
      tw[wi] = (uint32_t)x.x | ((uint32_t)x.y << 8)
             | ((uint32_t)x.z << 16) | ((uint32_t)x.w << 24);
    }
  }
}

// ---------------------------------------------------------------------------
// Gather one j: 21 consecutive dwords at tile[c*22] via 10 aligned b64 +
// 1 b32, single base reg + imm offsets (0..80 B). Rule #18: consume only
// after in-asm lgkmcnt(0) + sched_barrier(0).
// ---------------------------------------------------------------------------
#define RD64(dst, p, OFS) \
  asm volatile("ds_read_b64 %0, %1 offset:" #OFS \
               : "=v"(dst) : "v"((lf3_t)(p)))

__device__ __forceinline__ void gather_j(
    const float* __restrict__ tile, int c, float (&lg)[QQ]) {
  const float* p = tile + c * ROWDW;   // byte addr 88*c: 8B-aligned
  f32x2 g0, g1, g2, g3, g4, g5, g6, g7, g8, g9;
  float g20;
  RD64(g0, p, 0);  RD64(g1, p, 8);  RD64(g2, p, 16); RD64(g3, p, 24);
  RD64(g4, p, 32); RD64(g5, p, 40); RD64(g6, p, 48); RD64(g7, p, 56);
  RD64(g8, p, 64); RD64(g9, p, 72);
  asm volatile("ds_read_b32 %0, %1 offset:80" : "=v"(g20) : "v"((lf3_t)p));
  asm volatile("s_waitcnt lgkmcnt(0)" ::: "memory");
  __builtin_amdgcn_sched_barrier(0);
  lg[0]  += g0.x; lg[1]  += g0.y; lg[2]  += g1.x; lg[3]  += g1.y;
  lg[4]  += g2.x; lg[5]  += g2.y; lg[6]  += g3.x; lg[7]  += g3.y;
  lg[8]  += g4.x; lg[9]  += g4.y; lg[10] += g5.x; lg[11] += g5.y;
  lg[12] += g6.x; lg[13] += g6.y; lg[14] += g7.x; lg[15] += g7.y;
  lg[16] += g8.x; lg[17] += g8.y; lg[18] += g9.x; lg[19] += g9.y;
  lg[20] += g20;
}

// ---------------------------------------------------------------------------
// One segment: lg[a] += J[i,a,j,b(n,j)] over j in [jbeg, jend), jbeg%4==0.
// NBUF=2, one barrier/tile. Per iter: issue reg-stage loads (s+1) + token
// prefetch (s+2) BEFORE the gather (sched_barrier-pinned); write after the
// gather (compiler inserts the vmcnt wait at first jr use — covered by the
// ~1k-cyc gather). Early stores into buf[cur^1] are safe: its readers
// drained at the previous barrier.
// ---------------------------------------------------------------------------
template <int USET>
__device__ __forceinline__ void logz_seg(
    const float* __restrict__ Ji, const uint32_t* __restrict__ tokP,
    const int* __restrict__ Xtok, int jbeg, int jend, int n,
    float (*lds)[TILE_DW], float (&lg)[QQ], int t) {
  const int ntiles = (jend - jbeg + TJ - 1) / TJ;   // >= 1
  const int tl = t & 255, hi = t >> 8;              // hi wave-uniform
  const int wdw = (tl < CPT) ? (tl * ROWDW + (hi ? 12 : 0))
                             : (DUMP_DW + (hi ? 12 : 0));
  float* const wpA = &lds[0][wdw];
  float* const wpB = &lds[1][wdw];

  uint32_t cw[3], nx[3], nn[3];
  float jr[12];

  // Prologue: stage tile 0 into buf0; tokens for tiles 0,1.
  stage_load(Ji, jbeg, tl, hi, jr);
  tok_words<USET>(tokP, Xtok, jbeg, jbeg, jend, n, cw);
  tok_words<USET>(tokP, Xtok, jbeg + TJ, jbeg, jend, n, nx);
  stage_write(wpA, hi, jr);
  asm volatile("s_waitcnt lgkmcnt(0)" ::: "memory");
  __builtin_amdgcn_s_barrier();
  __builtin_amdgcn_sched_barrier(0);

  int cur = 0;
  for (int s = 0; s < ntiles; ++s) {
    const int rem  = min(TJ, jend - (jbeg + s * TJ));
    const bool more = (s + 1 < ntiles);             // block-uniform
    if (more) stage_load(Ji, jbeg + (s + 1) * TJ, tl, hi, jr);
    tok_words<USET>(tokP, Xtok, jbeg + (s + 2) * TJ, jbeg, jend, n, nn);
    __builtin_amdgcn_sched_barrier(0);              // pin loads above gather
    const float* tb = cur ? lds[1] : lds[0];
    #pragma unroll
    for (int jl = 0; jl < TJ; ++jl) {
      if (jl >= rem) break;                         // block-uniform
      const int b = (int)((cw[jl >> 2] >> ((jl & 3) * 8)) & 0xFF);
      gather_j(tb, jl * QQ + b, lg);
    }
    if (more) stage_write(cur ? wpA : wpB, hi, jr); // into buf[cur^1]
    #pragma unroll
    for (int wi = 0; wi < 3; ++wi) { cw[wi] = nx[wi]; nx[wi] = nn[wi]; }
    asm volatile("s_waitcnt lgkmcnt(0)" ::: "memory");
    __builtin_amdgcn_s_barrier();
    __builtin_amdgcn_sched_barrier(0);
    cur ^= 1;
  }
}

// ---------------------------------------------------------------------------
// p1 block: balanced quad-schedule per z-half. Range r owns quads
// [r*Tz/NB_R, (r+1)*Tz/NB_R); spans <=2 sites; atomic-flush into slab.
// ---------------------------------------------------------------------------
__device__ __forceinline__ void p1_block(
    const float* __restrict__ J, const uint32_t* __restrict__ tokP,
    float* __restrict__ slab, int bx, float (*lds)[TILE_DW]) {
  const int t = threadIdx.x;
  const int r = bx & (NB_R - 1);
  const int z = bx >> 8;

  int Tz = 0;                          // constant-folds
  #pragma unroll
  for (int s2 = 0; s2 < NS; ++s2) Tz += (START + s2 + 3) >> 2;

  int g  = (r * Tz) / NB_R;
  const int g1 = ((r + 1) * Tz) / NB_R;
  int iI = 0, pref = 0;
  while (pref + ((START + iI + 3) >> 2) <= g) {
    pref += (START + iI + 3) >> 2;
    ++iI;
  }
  int qlo = g - pref;

  float lg[QQ];
  #pragma unroll
  for (int a = 0; a < QQ; ++a) lg[a] = 0.0f;

  while (g < g1) {
    const int i    = START + iI;
    const int qcap = (i + 3) >> 2;
    int qhi = qlo + (g1 - g);
    if (qhi > qcap) qhi = qcap;
    const int jbeg = qlo * 4;
    int jend = qhi * 4; if (jend > i) jend = i;
    const int n = z * BT + t;
    const float* Ji = J + (size_t)i * (QQ * LL * QQ);

    logz_seg<1>(Ji, tokP, nullptr, jbeg, jend, n, lds, lg, t);

    float* dst = slab + ((size_t)iI * QQ) * MM + n;
    #pragma unroll
    for (int a = 0; a < QQ; ++a) { atomicAdd(dst + a * MM, lg[a]); lg[a] = 0.0f; }

    g += qhi - qlo;
    qlo = 0; ++iI;
  }
}

// ---------------------------------------------------------------------------
// jsum body: sum(J^2) stream + sum(J*fij) prefix rows, grid-strided by jb.
// ---------------------------------------------------------------------------
__device__ __forceinline__ void jsum_body(
    const float* __restrict__ J, const float* __restrict__ fij,
    float* __restrict__ acc, int jb) {
  const int t = threadIdx.x;
  const float4* __restrict__ J4 = (const float4*)J;
  float j2 = 0.0f;
  for (int f = jb * BT + t; f < (LL * QQ * LL * QQ / 4); f += NB_JS * BT) {
    const float4 v = J4[f];
    j2 += v.x * v.x + v.y * v.y + v.z * v.z + v.w * v.w;
  }
  float e = 0.0f;
  for (int r = jb; r < NS * QQ; r += NB_JS) {
    const int iI = r / QQ;
    const int a  = r - iI * QQ;
    const int i  = START + iI;
    const size_t base = (size_t)i * (QQ * LL * QQ) + (size_t)a * (LL * QQ);
    const float4* __restrict__ Jb = (const float4*)(J + base);
    const float4* __restrict__ Fb = (const float4*)(fij + base);
    const int lim  = i * QQ;
    const int lim4 = lim >> 2;
    for (int f = t; f < lim4; f += BT) {
      const float4 v = Jb[f], u = Fb[f];
      e += v.x * u.x + v.y * u.y + v.z * u.z + v.w * u.w;
    }
    const int rem = lim & 3;
    if (t < rem) {
      const int p = lim4 * 4 + t;
      e += (J + base)[p] * (fij + base)[p];
    }
  }
  const float tj2 = block_reduce_sum<NWAVE>(j2);
  const float te  = block_reduce_sum<NWAVE>(e);
  if (t == 0) {
    atomicAdd(acc + SLOT_J2 + (jb & 63), tj2);
    atomicAdd(acc + SLOT_E  + (jb & 63), te);
  }
}

// ---------------------------------------------------------------------------
// Fused kernel: blocks [0, NB_P1) = p1 (2 z-paired per CU), then jsum
// fillers (HBM-bound) on the 3rd block slot + makespan tail.
// ---------------------------------------------------------------------------
__global__ __launch_bounds__(BT, 6) void kern_mega(
    const float* __restrict__ J, const float* __restrict__ fij,
    const uint32_t* __restrict__ tokP, float* __restrict__ slab,
    float* __restrict__ acc) {
  __shared__ float lds[NBUF][TILE_DW];
  const int bx = blockIdx.x;
  if (bx < NB_P1) p1_block(J, tokP, slab, bx, lds);
  else            jsum_body(J, fij, acc, bx - NB_P1);
}

// ---------------------------------------------------------------------------
// Fallback (ws too small for slab): full-range mono blocks with in-kernel
// logsumexp. Grid (NS, 1, 2), z = blockIdx.z.
// ---------------------------------------------------------------------------
template <int USET>
__device__ __forceinline__ void mono_body(
    const float* __restrict__ J, const uint32_t* __restrict__ tokP,
    const int* __restrict__ Xtok, const float* __restrict__ h,
    const float* __restrict__ w, float* __restrict__ acc,
    float (*lds)[TILE_DW]) {
  const int iI = blockIdx.x;
  const int i  = START + iI;
  const int t  = threadIdx.x;
  const int n  = blockIdx.z * BT + t;
  float lg[QQ];
  #pragma unroll
  for (int a = 0; a < QQ; ++a) lg[a] = 0.0f;
  logz_seg<USET>(J + (size_t)i * (QQ * LL * QQ), tokP, Xtok, 0, i, n,
                 lds, lg, t);
  const float* hi = h + i * QQ;
  float mx = -3.0e38f;
  #pragma unroll
  for (int a = 0; a < QQ; ++a) { lg[a] += hi[a]; mx = fmaxf(mx, lg[a]); }
  float sme = 0.0f;
  #pragma unroll
  for (int a = 0; a < QQ; ++a) sme += expf(lg[a] - mx);
  const float contrib = w[n] * (mx + logf(sme));
  const float tot = block_reduce_sum<NWAVE>(contrib);
  if (t == 0) atomicAdd(acc + SLOT_LZ + (iI & 63), tot);
}

__global__ __launch_bounds__(BT) void kern_logz_mono_t(
    const float* __restrict__ J, const uint32_t* __restrict__ tokP,
    const float* __restrict__ h, const float* __restrict__ w,
    float* __restrict__ acc) {
  __shared__ float lds[NBUF][TILE_DW];
  mono_body<1>(J, tokP, nullptr, h, w, acc, lds);
}

__global__ __launch_bounds__(BT) void kern_logz_mono_x(
    const float* __restrict__ J, const int* __restrict__ Xtok,
    const float* __restrict__ h, const float* __restrict__ w,
    float* __restrict__ acc) {
  __shared__ float lds[NBUF][TILE_DW];
  mono_body<0>(J, nullptr, Xtok, h, w, acc, lds);
}

__global__ __launch_bounds__(BT) void kern_jsum(
    const float* __restrict__ J, const float* __restrict__ fij,
    float* __restrict__ acc) {
  jsum_body(J, fij, acc, blockIdx.x);
}

// ---------------------------------------------------------------------------
// Phase 2: slab + h -> logsumexp -> weighted sum (fence-free).
// ---------------------------------------------------------------------------
__global__ __launch_bounds__(128) void kern_logz_p2(
    const float* __restrict__ slab, const float* __restrict__ h,
    const float* __restrict__ w, float* __restrict__ acc) {
  const int iI = blockIdx.x;
  const int n  = blockIdx.y * 128 + threadIdx.x;
  const float* s0 = slab + ((size_t)iI * QQ) * MM + n;
  const float* hi = h + (START + iI) * QQ;
  float lg[QQ];
  float mx = -3.0e38f;
  #pragma unroll
  for (int a = 0; a < QQ; ++a) {
    lg[a] = s0[a * MM] + hi[a];
    mx = fmaxf(mx, lg[a]);
  }
  float sme = 0.0f;
  #pragma unroll
  for (int a = 0; a < QQ; ++a) sme += expf(lg[a] - mx);
  float v = w[n] * (mx + logf(sme));
  #pragma unroll
  for (int off = 32; off > 0; off >>= 1) v += __shfl_down(v, off, 64);
  __shared__ float sm[2];
  if ((threadIdx.x & 63) == 0) sm[threadIdx.x >> 6] = v;
  __syncthreads();
  if (threadIdx.x == 0)
    atomicAdd(acc + SLOT_LZ + ((iI * 8 + blockIdx.y) & 63), sm[0] + sm[1]);
}

// ---------------------------------------------------------------------------
// Token packing + accumulator/slab zeroing.
// ---------------------------------------------------------------------------
__global__ __launch_bounds__(256) void kern_tokP(
    const int* __restrict__ X, uint32_t* __restrict__ tokP,
    float* __restrict__ slab, float* __restrict__ acc, int zslab) {
  const int idx = blockIdx.x * 256 + threadIdx.x;
  if (blockIdx.x == 0) acc[threadIdx.x] = 0.0f;
  if (idx < (LL / 4) * MM) {
    const int jq = idx / MM;
    const int n  = idx - jq * MM;
    const int4 x = *reinterpret_cast<const int4*>(X + n * LL + 4 * jq);
    tokP[idx] = (uint32_t)x.x | ((uint32_t)x.y << 8)
              | ((uint32_t)x.z << 16) | ((uint32_t)x.w << 24);
  }
  if (zslab) {
    float4* s4 = (float4*)slab;
    const int nf4 = (int)(SLAB_FLOATS / 4);
    for (int q = idx; q < nf4; q += NB_TOKP * 256)
      s4[q] = make_float4(0.f, 0.f, 0.f, 0.f);
  }
}

// ---------------------------------------------------------------------------
// Final combine: slot sums + h-side terms + weight normalization.
// ---------------------------------------------------------------------------
__global__ __launch_bounds__(256) void kern_final(
    const float* __restrict__ h, const float* __restrict__ fi,
    const float* __restrict__ w, const float* __restrict__ acc,
    float* __restrict__ out) {
  const int t = threadIdx.x;
  const float sj2 = block_reduce_sum<4>(t < 64 ? acc[SLOT_J2 + t] : 0.0f);
  const float se  = block_reduce_sum<4>(t < 64 ? acc[SLOT_E + t] : 0.0f);
  const float slz = block_reduce_sum<4>(t < 64 ? acc[SLOT_LZ + t] : 0.0f);
  float hs = 0.0f, eh = 0.0f, ws = 0.0f;
  for (int idx = t; idx < LL * QQ; idx += 256) {
    const float hv = h[idx];
    hs += hv * hv;
    if (idx >= START * QQ) eh += fi[idx] * hv;
  }
  for (int idx = t; idx < MM; idx += 256) ws += w[idx];
  const float ths = block_reduce_sum<4>(hs);
  const float teh = block_reduce_sum<4>(eh);
  const float tws = block_reduce_sum<4>(ws);
  if (t == 0) {
    const float energy = teh + se;
    const float nll = slz / tws - energy;
    out[0] = nll + RGH * ths + RGJ * sj2;
    out[1] = nll;
  }
}

extern "C" void kernel_launch(void* const* d_in, const int* in_sizes, int n_in,
                              void* d_out, int out_size, void* d_ws, size_t ws_size,
                              hipStream_t stream) {
  const int*   Xtok = (const int*)  d_in[0];
  const float* wts  = (const float*)d_in[1];
  const float* fi   = (const float*)d_in[2];
  const float* fij  = (const float*)d_in[3];
  const float* h    = (const float*)d_in[4];
  const float* J    = (const float*)d_in[5];
  float* out  = (float*)d_out;
  float* acc  = (float*)d_ws;
  uint32_t* tokP = (uint32_t*)((char*)d_ws + TOKP_OFF);
  float* slab = (float*)((char*)d_ws + SLAB_OFF);

  if (ws_size >= WS_FULL) {
    kern_tokP<<<NB_TOKP, 256, 0, stream>>>(Xtok, tokP, slab, acc, 1);
    kern_mega<<<NB_P1 + NB_JS, BT, 0, stream>>>(J, fij, tokP, slab, acc);
    kern_logz_p2<<<dim3(NS, 8), 128, 0, stream>>>(slab, h, wts, acc);
    kern_final<<<1, 256, 0, stream>>>(h, fi, wts, acc, out);
  } else if (ws_size >= WS_TOK) {
    kern_tokP<<<NB_TOKP, 256, 0, stream>>>(Xtok, tokP, nullptr, acc, 0);
    kern_jsum<<<NB_JS, BT, 0, stream>>>(J, fij, acc);
    kern_logz_mono_t<<<dim3(NS, 1, 2), BT, 0, stream>>>(J, tokP, h, wts, acc);
    kern_final<<<1, 256, 0, stream>>>(h, fi, wts, acc, out);
  } else {
    hipMemsetAsync(d_ws, 0, 1024, stream);
    kern_jsum<<<NB_JS, BT, 0, stream>>>(J, fij, acc);
    kern_logz_mono_x<<<dim3(NS, 1, 2), BT, 0, stream>>>(J, Xtok, h, wts, acc);
    kern_final<<<1, 256, 0, stream>>>(h, fi, wts, acc, out);
  }
}